// Round 3
// baseline (323.030 us; speedup 1.0000x reference)
//
#include <hip/hip_runtime.h>

// LoRA embedding: out = E[idx] + (E[idx] @ A) @ B + bias
//   idx:[T] i32, E:[50257,1024] f32, A:[1024,8] f32, B:[8,1024] f32,
//   bias:[1024] f32, out:[T,1024] f32
//
// 4 waves per token (quarter-row each). Each thread owns a FIXED float4
// column f4 = quarter*64 + lane across a grid-stride token loop, so the
// A-fragment (4f x 8r = 32 VGPR), B-fragment (8r x 4f = 32 VGPR) and bias
// live in registers, loaded once. Per-token LDS = 160 B (cross-wave partial
// exchange) instead of 64 KB of A/B re-reads. Reduction: 7-shuffle
// reduce-scatter + 3-stage cross-group butterfly (10 DS ops vs 48).

constexpr int F  = 1024;
constexpr int R  = 8;
constexpr int F4 = F / 4;        // 256 float4 per row
constexpr int TPB  = 256;        // 4 waves = the 4 quarters of one token
constexpr int NBLK = 2048;       // grid-stride over tokens

__global__ __launch_bounds__(TPB, 4)
void lora_emb_kernel(const int* __restrict__ idx,
                     const float* __restrict__ emb,
                     const float* __restrict__ A,
                     const float* __restrict__ Bm,
                     const float* __restrict__ bias,
                     float* __restrict__ out,
                     int ntok)
{
    __shared__ float ldsP[2][4][R];           // [buf][quarter][r] : 256 B

    const int lane    = threadIdx.x & 63;
    const int quarter = threadIdx.x >> 6;
    const int f4      = quarter * 64 + lane;  // fixed column (float4 units)

    // ---- one-time register-resident operand fragments ----
    float a_frag[4][8];                       // [j][r] = A[4*f4+j][r]
    #pragma unroll
    for (int j = 0; j < 4; ++j) {
        const float* ap = A + (size_t)(4 * f4 + j) * R;
        const float4 lo = *reinterpret_cast<const float4*>(ap);
        const float4 hi = *reinterpret_cast<const float4*>(ap + 4);
        a_frag[j][0] = lo.x; a_frag[j][1] = lo.y; a_frag[j][2] = lo.z; a_frag[j][3] = lo.w;
        a_frag[j][4] = hi.x; a_frag[j][5] = hi.y; a_frag[j][6] = hi.z; a_frag[j][7] = hi.w;
    }
    float b_frag[8][4];                       // [r][c] = B[r][4*f4+c]
    #pragma unroll
    for (int r = 0; r < 8; ++r) {
        const float4 b = *reinterpret_cast<const float4*>(Bm + (size_t)r * F + 4 * f4);
        b_frag[r][0] = b.x; b_frag[r][1] = b.y; b_frag[r][2] = b.z; b_frag[r][3] = b.w;
    }
    const float4 bi = *reinterpret_cast<const float4*>(bias + 4 * f4);

    const float4* emb4 = reinterpret_cast<const float4*>(emb);
    float4*       out4 = reinterpret_cast<float4*>(out);

    const int stride = gridDim.x;
    int t = blockIdx.x;
    if (t >= ntok) return;                    // block-uniform

    // software pipeline: current row value v, next row index prefetched
    int   t1      = t + stride;
    int   row_nxt = (t1 < ntok) ? idx[t1] : 0;
    float4 v      = emb4[(size_t)idx[t] * F4 + f4];

    const bool s1 = (lane & 1) != 0;
    const bool s2 = (lane & 2) != 0;
    const bool s4 = (lane & 4) != 0;
    // r held after reduce-scatter = bit-reversal of (lane&7)
    const int  rr = ((lane & 1) << 2) | (lane & 2) | ((lane >> 2) & 1);

    int buf = 0;
    while (true) {
        // ---- prefetch next token's row (hides idx->gather chain) ----
        const bool hasn = (t1 < ntok);        // block-uniform
        float4 vn;
        if (hasn) vn = emb4[(size_t)row_nxt * F4 + f4];
        const int t2     = t1 + stride;
        const int row_n2 = (t2 < ntok) ? idx[t2] : 0;

        // ---- per-lane partial dots: p[r] = dot(v, A[f(lane)..][r]) ----
        float p[8];
        #pragma unroll
        for (int r = 0; r < 8; ++r)
            p[r] = v.x * a_frag[0][r] + v.y * a_frag[1][r]
                 + v.z * a_frag[2][r] + v.w * a_frag[3][r];

        // ---- reduce-scatter over r within 8-lane groups (7 shuffles) ----
        float q[4];
        #pragma unroll
        for (int j = 0; j < 4; ++j) {
            const float send = s1 ? p[j]     : p[j + 4];
            const float keep = s1 ? p[j + 4] : p[j];
            q[j] = keep + __shfl_xor(send, 1, 64);
        }
        float w2[2];
        #pragma unroll
        for (int j = 0; j < 2; ++j) {
            const float send = s2 ? q[j]     : q[j + 2];
            const float keep = s2 ? q[j + 2] : q[j];
            w2[j] = keep + __shfl_xor(send, 2, 64);
        }
        float s = (s4 ? w2[1] : w2[0]) + __shfl_xor(s4 ? w2[0] : w2[1], 4, 64);
        // ---- cross-group butterfly: wave-level partial for r = rr ----
        s += __shfl_xor(s, 8, 64);
        s += __shfl_xor(s, 16, 64);
        s += __shfl_xor(s, 32, 64);

        if (lane < 8) ldsP[buf][quarter][rr] = s;
        __syncthreads();

        // ---- sum the 4 quarter-partials (broadcast b128 reads) ----
        float pall[8];
        {
            const float4* pb = reinterpret_cast<const float4*>(&ldsP[buf][0][0]);
            const float4 l0 = pb[0], h0 = pb[1];
            const float4 l1 = pb[2], h1 = pb[3];
            const float4 l2 = pb[4], h2 = pb[5];
            const float4 l3 = pb[6], h3 = pb[7];
            pall[0] = l0.x + l1.x + l2.x + l3.x;
            pall[1] = l0.y + l1.y + l2.y + l3.y;
            pall[2] = l0.z + l1.z + l2.z + l3.z;
            pall[3] = l0.w + l1.w + l2.w + l3.w;
            pall[4] = h0.x + h1.x + h2.x + h3.x;
            pall[5] = h0.y + h1.y + h2.y + h3.y;
            pall[6] = h0.z + h1.z + h2.z + h3.z;
            pall[7] = h0.w + h1.w + h2.w + h3.w;
        }

        // ---- epilogue: out = v + bias + sum_r pall[r] * B[r][cols] ----
        const float vv[4] = { v.x, v.y, v.z, v.w };
        const float bb[4] = { bi.x, bi.y, bi.z, bi.w };
        float o[4];
        #pragma unroll
        for (int c = 0; c < 4; ++c) {
            float acc = vv[c] + bb[c];
            #pragma unroll
            for (int r = 0; r < 8; ++r) acc += pall[r] * b_frag[r][c];
            o[c] = acc;
        }
        out4[(size_t)t * F4 + f4] = make_float4(o[0], o[1], o[2], o[3]);

        if (!hasn) break;                     // block-uniform exit
        v = vn; t = t1; t1 = t2; row_nxt = row_n2; buf ^= 1;
    }
}

extern "C" void kernel_launch(void* const* d_in, const int* in_sizes, int n_in,
                              void* d_out, int out_size, void* d_ws, size_t ws_size,
                              hipStream_t stream) {
    const int*   idx  = (const int*)  d_in[0];
    const float* emb  = (const float*)d_in[1];
    const float* A    = (const float*)d_in[2];
    const float* Bm   = (const float*)d_in[3];
    const float* bias = (const float*)d_in[4];
    float* out = (float*)d_out;

    const int ntok = in_sizes[0];             // 8*4096 = 32768
    int blocks = NBLK;
    if (blocks > ntok) blocks = ntok;

    hipLaunchKernelGGL(lora_emb_kernel, dim3(blocks), dim3(TPB), 0, stream,
                       idx, emb, A, Bm, bias, out, ntok);
}

// Round 5
// 318.634 us; speedup vs baseline: 1.0138x; 1.0138x over previous
//
#include <hip/hip_runtime.h>

// LoRA embedding: out = E[idx] + (E[idx] @ A) @ B + bias
//   idx:[T] i32, E:[50257,1024] f32, A:[1024,8] f32, B:[8,1024] f32,
//   bias:[1024] f32, out:[T,1024] f32
//
// 4 waves per token (quarter-row each); thread owns fixed float4 column
// f4 = quarter*64 + lane across a grid-stride token loop. A-fragment
// (32 VGPR), B-fragment (32 VGPR), bias (4 VGPR) loaded once.
//
// R3 fix: __syncthreads() drains vmcnt(0) (compiler emits full waitcnt
// before s_barrier), which nullified the gather prefetch every iteration.
// Replaced with raw s_barrier + explicit lgkmcnt(0) (only the 32 B LDS
// partial exchange needs ordering; ldsP is double-buffered so one barrier
// per iteration is race-free). Prefetch deepened to 2 tokens so ~900 cy of
// HBM gather latency hides under two iterations of compute. Output stores
// are nontemporal so 134 MB of streaming writes don't evict E from L3.

typedef float f32x4 __attribute__((ext_vector_type(4)));

constexpr int F  = 1024;
constexpr int R  = 8;
constexpr int F4 = F / 4;        // 256 float4 per row
constexpr int TPB  = 256;        // 4 waves = 4 quarters of one token
constexpr int NBLK = 2048;       // grid-stride over tokens (16 iters/block)

__global__ __launch_bounds__(TPB, 4)
void lora_emb_kernel(const int* __restrict__ idx,
                     const float* __restrict__ emb,
                     const float* __restrict__ A,
                     const float* __restrict__ Bm,
                     const float* __restrict__ bias,
                     float* __restrict__ out,
                     int ntok)
{
    __shared__ float ldsP[2][4][R];           // [buf][quarter][r] : 256 B

    const int lane    = threadIdx.x & 63;
    const int quarter = threadIdx.x >> 6;
    const int f4      = quarter * 64 + lane;  // fixed column (float4 units)

    // ---- one-time register-resident operand fragments ----
    float a_frag[4][8];                       // [j][r] = A[4*f4+j][r]
    #pragma unroll
    for (int j = 0; j < 4; ++j) {
        const float* ap = A + (size_t)(4 * f4 + j) * R;
        const f32x4 lo = *reinterpret_cast<const f32x4*>(ap);
        const f32x4 hi = *reinterpret_cast<const f32x4*>(ap + 4);
        a_frag[j][0] = lo.x; a_frag[j][1] = lo.y; a_frag[j][2] = lo.z; a_frag[j][3] = lo.w;
        a_frag[j][4] = hi.x; a_frag[j][5] = hi.y; a_frag[j][6] = hi.z; a_frag[j][7] = hi.w;
    }
    float b_frag[8][4];                       // [r][c] = B[r][4*f4+c]
    #pragma unroll
    for (int r = 0; r < 8; ++r) {
        const f32x4 b = *reinterpret_cast<const f32x4*>(Bm + (size_t)r * F + 4 * f4);
        b_frag[r][0] = b.x; b_frag[r][1] = b.y; b_frag[r][2] = b.z; b_frag[r][3] = b.w;
    }
    const f32x4 bi = *reinterpret_cast<const f32x4*>(bias + 4 * f4);

    const f32x4* emb4 = reinterpret_cast<const f32x4*>(emb);
    f32x4*       out4 = reinterpret_cast<f32x4*>(out);

    const int stride = gridDim.x;
    int t0 = blockIdx.x;
    if (t0 >= ntok) return;                   // block-uniform

    // ---- 2-deep software pipeline over the gather ----
    int t1 = t0 + stride;
    int t2 = t1 + stride;
    f32x4 v = emb4[(size_t)idx[t0] * F4 + f4];
    f32x4 vn;
    const bool h1_init = (t1 < ntok);
    if (h1_init) vn = emb4[(size_t)idx[t1] * F4 + f4];
    int row2 = (t2 < ntok) ? idx[t2] : 0;
    bool h1 = h1_init;

    const bool s1 = (lane & 1) != 0;
    const bool s2 = (lane & 2) != 0;
    const bool s4 = (lane & 4) != 0;
    // r held after reduce-scatter = bit-reversal of (lane&7)
    const int  rr = ((lane & 1) << 2) | (lane & 2) | ((lane >> 2) & 1);

    int buf = 0;
    while (true) {
        // ---- issue gather for token t+2 (stays in flight across barrier) ----
        const bool h2 = (t2 < ntok);          // block-uniform
        f32x4 vn2;
        if (h2) vn2 = emb4[(size_t)row2 * F4 + f4];
        const int t3   = t2 + stride;
        const int row3 = (t3 < ntok) ? idx[t3] : 0;

        // ---- per-lane partial dots: p[r] = dot(v, A[f(lane)..][r]) ----
        float p[8];
        #pragma unroll
        for (int r = 0; r < 8; ++r)
            p[r] = v.x * a_frag[0][r] + v.y * a_frag[1][r]
                 + v.z * a_frag[2][r] + v.w * a_frag[3][r];

        // ---- reduce-scatter over r within 8-lane groups (7 shuffles) ----
        float q[4];
        #pragma unroll
        for (int j = 0; j < 4; ++j) {
            const float send = s1 ? p[j]     : p[j + 4];
            const float keep = s1 ? p[j + 4] : p[j];
            q[j] = keep + __shfl_xor(send, 1, 64);
        }
        float w2[2];
        #pragma unroll
        for (int j = 0; j < 2; ++j) {
            const float send = s2 ? q[j]     : q[j + 2];
            const float keep = s2 ? q[j + 2] : q[j];
            w2[j] = keep + __shfl_xor(send, 2, 64);
        }
        float s = (s4 ? w2[1] : w2[0]) + __shfl_xor(s4 ? w2[0] : w2[1], 4, 64);
        // ---- cross-group butterfly: wave-level partial for r = rr ----
        s += __shfl_xor(s, 8, 64);
        s += __shfl_xor(s, 16, 64);
        s += __shfl_xor(s, 32, 64);

        if (lane < 8) ldsP[buf][quarter][rr] = s;
        // Order ONLY the ds_write, then raw barrier: the in-flight global
        // gathers (vn/vn2) are NOT drained (vs __syncthreads' vmcnt(0)).
        asm volatile("s_waitcnt lgkmcnt(0)" ::: "memory");
        __builtin_amdgcn_s_barrier();
        asm volatile("" ::: "memory");

        // ---- sum the 4 quarter-partials (broadcast b128 reads) ----
        float pall[8];
        {
            const f32x4* pb = reinterpret_cast<const f32x4*>(&ldsP[buf][0][0]);
            const f32x4 l0 = pb[0], h0 = pb[1];
            const f32x4 l1 = pb[2], h1r = pb[3];
            const f32x4 l2 = pb[4], h2r = pb[5];
            const f32x4 l3 = pb[6], h3r = pb[7];
            pall[0] = l0.x + l1.x + l2.x + l3.x;
            pall[1] = l0.y + l1.y + l2.y + l3.y;
            pall[2] = l0.z + l1.z + l2.z + l3.z;
            pall[3] = l0.w + l1.w + l2.w + l3.w;
            pall[4] = h0.x + h1r.x + h2r.x + h3r.x;
            pall[5] = h0.y + h1r.y + h2r.y + h3r.y;
            pall[6] = h0.z + h1r.z + h2r.z + h3r.z;
            pall[7] = h0.w + h1r.w + h2r.w + h3r.w;
        }

        // ---- epilogue: out = v + bias + sum_r pall[r] * B[r][cols] ----
        const float vv[4] = { v.x, v.y, v.z, v.w };
        const float bb[4] = { bi.x, bi.y, bi.z, bi.w };
        float o[4];
        #pragma unroll
        for (int c = 0; c < 4; ++c) {
            float acc = vv[c] + bb[c];
            #pragma unroll
            for (int r = 0; r < 8; ++r) acc += pall[r] * b_frag[r][c];
            o[c] = acc;
        }
        f32x4 ov; ov.x = o[0]; ov.y = o[1]; ov.z = o[2]; ov.w = o[3];
        __builtin_nontemporal_store(ov, out4 + (size_t)t0 * F4 + f4);

        if (!h1) break;                       // block-uniform exit
        v = vn; vn = vn2; h1 = h2;
        t0 = t1; t1 = t2; t2 = t3; row2 = row3;
        buf ^= 1;
    }
}

extern "C" void kernel_launch(void* const* d_in, const int* in_sizes, int n_in,
                              void* d_out, int out_size, void* d_ws, size_t ws_size,
                              hipStream_t stream) {
    const int*   idx  = (const int*)  d_in[0];
    const float* emb  = (const float*)d_in[1];
    const float* A    = (const float*)d_in[2];
    const float* Bm   = (const float*)d_in[3];
    const float* bias = (const float*)d_in[4];
    float* out = (float*)d_out;

    const int ntok = in_sizes[0];             // 8*4096 = 32768
    int blocks = NBLK;
    if (blocks > ntok) blocks = ntok;

    hipLaunchKernelGGL(lora_emb_kernel, dim3(blocks), dim3(TPB), 0, stream,
                       idx, emb, A, Bm, bias, out, ntok);
}